// Round 12
// baseline (304.332 us; speedup 1.0000x reference)
//
#include <hip/hip_runtime.h>
#include <hip/hip_bf16.h>

#define MESH   128
#define MESH2  16384
#define MESH3  2097152
// paint tile: 16x16x16 core, halo 2 each side -> span 21 per axis
#define SP 21
#define CELLS (SP * SP * SP)   // 9261 floats = 36.2 KB
#define PSTR 129               // LDS plane row stride (float2): bank-conflict pad

// ---------- helpers ----------
__device__ __forceinline__ float kfreq(int i) {
    int s = (i < 64) ? i : (i - 128);
    return 0.049087385212340517f * (float)s;   // 2*pi*fftfreq(128)[i]
}

__device__ __forceinline__ float load_elem(const void* p, int i, int isbf16) {
    if (isbf16) return __bfloat162float(((const __hip_bfloat16*)p)[i]);
    return ((const float*)p)[i];
}

__device__ __forceinline__ float bf2f(unsigned short u) {
    unsigned int w = ((unsigned int)u) << 16;
    return __uint_as_float(w);
}

// Native FP atomics via inline asm (paint sits at the LDS atomic-RMW floor;
// proven invariant across R0-R6).
__device__ __forceinline__ void ldsAddF(float* p, float v) {
    unsigned off = (unsigned)(unsigned long long)p;
    asm volatile("ds_add_f32 %0, %1" :: "v"(off), "v"(v) : "memory");
}
__device__ __forceinline__ void glbAddF(float* p, float v) {
    asm volatile("global_atomic_add_f32 %0, %1, off" :: "v"(p), "v"(v) : "memory");
}

// 8-point DFT in registers, natural order, e^{sgn*2pi*i*nk/8}
__device__ __forceinline__ void dft8(float2* a, float sgn) {
    const float r = 0.70710678118654752f;
    float2 b0 = a[0], b1 = a[4], b2 = a[2], b3 = a[6];
    float2 b4 = a[1], b5 = a[5], b6 = a[3], b7 = a[7];
    float2 c0 = make_float2(b0.x + b1.x, b0.y + b1.y);
    float2 c1 = make_float2(b0.x - b1.x, b0.y - b1.y);
    float2 c2 = make_float2(b2.x + b3.x, b2.y + b3.y);
    float2 c3 = make_float2(b2.x - b3.x, b2.y - b3.y);
    float2 c4 = make_float2(b4.x + b5.x, b4.y + b5.y);
    float2 c5 = make_float2(b4.x - b5.x, b4.y - b5.y);
    float2 c6 = make_float2(b6.x + b7.x, b6.y + b7.y);
    float2 c7 = make_float2(b6.x - b7.x, b6.y - b7.y);
    float2 t3 = make_float2(-sgn * c3.y, sgn * c3.x);
    float2 t7 = make_float2(-sgn * c7.y, sgn * c7.x);
    float2 d0 = make_float2(c0.x + c2.x, c0.y + c2.y);
    float2 d2 = make_float2(c0.x - c2.x, c0.y - c2.y);
    float2 d1 = make_float2(c1.x + t3.x, c1.y + t3.y);
    float2 d3 = make_float2(c1.x - t3.x, c1.y - t3.y);
    float2 d4 = make_float2(c4.x + c6.x, c4.y + c6.y);
    float2 d6 = make_float2(c4.x - c6.x, c4.y - c6.y);
    float2 d5 = make_float2(c5.x + t7.x, c5.y + t7.y);
    float2 d7 = make_float2(c5.x - t7.x, c5.y - t7.y);
    float2 w1 = make_float2(r, sgn * r), w3 = make_float2(-r, sgn * r);
    float2 t5 = make_float2(d5.x * w1.x - d5.y * w1.y, d5.x * w1.y + d5.y * w1.x);
    float2 t6 = make_float2(-sgn * d6.y, sgn * d6.x);
    float2 t7b = make_float2(d7.x * w3.x - d7.y * w3.y, d7.x * w3.y + d7.y * w3.x);
    a[0] = make_float2(d0.x + d4.x, d0.y + d4.y);
    a[4] = make_float2(d0.x - d4.x, d0.y - d4.y);
    a[1] = make_float2(d1.x + t5.x, d1.y + t5.y);
    a[5] = make_float2(d1.x - t5.x, d1.y - t5.y);
    a[2] = make_float2(d2.x + t6.x, d2.y + t6.y);
    a[6] = make_float2(d2.x - t6.x, d2.y - t6.y);
    a[3] = make_float2(d3.x + t7b.x, d3.y + t7b.y);
    a[7] = make_float2(d3.x - t7b.x, d3.y - t7b.y);
}

// ---------- 128-pt radix-8x16 FFT on an LDS plane line (in-place) ----------
// Line owned by ONE 16-lane intra-wave group (u = lane&15): the two-stage
// exchange goes through the line's own 128 slots with a rotated mapping
// slot(k1,j) = k1*16 + ((j + 2*k1) & 15)  (bijective per k1; bank-spread).
// Same-wave LDS ops are in-order -> no barriers needed.
__device__ __forceinline__ void fft128_plane(float2* pl, int lb, int stride,
                                             int u, float sgn) {
    float2 v[8];
#pragma unroll
    for (int n1 = 0; n1 < 8; ++n1) v[n1] = pl[lb + (16 * n1 + u) * stride];
    dft8(v, sgn);
#pragma unroll
    for (int k1 = 0; k1 < 8; ++k1) {
        float ang = sgn * 0.049087385212340517f * (float)(u * k1);
        float sn, cs; __sincosf(ang, &sn, &cs);
        float2 y = v[k1];
        int slot = k1 * 16 + ((u + 2 * k1) & 15);
        pl[lb + slot * stride] = make_float2(y.x * cs - y.y * sn, y.x * sn + y.y * cs);
    }
    asm volatile("" ::: "memory");   // keep LDS write->read order at compile level
    int k1 = u & 7, c = u >> 3;
    float2 w[8];
#pragma unroll
    for (int b = 0; b < 8; ++b) {
        float2 za = pl[lb + (k1 * 16 + ((b + 2 * k1) & 15)) * stride];
        float2 zb = pl[lb + (k1 * 16 + ((8 + b + 2 * k1) & 15)) * stride];
        float2 s = c ? make_float2(za.x - zb.x, za.y - zb.y)
                     : make_float2(za.x + zb.x, za.y + zb.y);
        if (c && b) {
            float ang = sgn * 0.39269908169872414f * (float)b;  // 2pi/16
            float sn, cs; __sincosf(ang, &sn, &cs);
            s = make_float2(s.x * cs - s.y * sn, s.x * sn + s.y * cs);
        }
        w[b] = s;
    }
    dft8(w, sgn);
    asm volatile("" ::: "memory");
#pragma unroll
    for (int k3 = 0; k3 < 8; ++k3) pl[lb + (u + 16 * k3) * stride] = w[k3];
}

// ---------- 128-pt FFT through a block-shared Z buffer (lines span waves) ----
// Thread (l,u): v[n1] = elem[16*n1+u] in, v[k3] = elem[u+16*k3] out.
// Leading __syncthreads makes Z reusable across consecutive calls.
__device__ __forceinline__ void fft128_Z(float2* Z, int l, int u, float sgn,
                                         float2* v) {
    __syncthreads();
    dft8(v, sgn);
#pragma unroll
    for (int k1 = 0; k1 < 8; ++k1) {
        float ang = sgn * 0.049087385212340517f * (float)(u * k1);
        float sn, cs; __sincosf(ang, &sn, &cs);
        float2 y = v[k1];
        Z[l * 137 + k1 * 17 + u] = make_float2(y.x * cs - y.y * sn, y.x * sn + y.y * cs);
    }
    __syncthreads();
    int k1 = u & 7, c = u >> 3;
    float2 w[8];
#pragma unroll
    for (int b = 0; b < 8; ++b) {
        float2 za = Z[l * 137 + k1 * 17 + b];
        float2 zb = Z[l * 137 + k1 * 17 + 8 + b];
        float2 s = c ? make_float2(za.x - zb.x, za.y - zb.y)
                     : make_float2(za.x + zb.x, za.y + zb.y);
        if (c && b) {
            float ang = sgn * 0.39269908169872414f * (float)b;  // 2pi/16
            float sn, cs; __sincosf(ang, &sn, &cs);
            s = make_float2(s.x * cs - s.y * sn, s.x * sn + s.y * cs);
        }
        w[b] = s;
    }
    dft8(w, sgn);
#pragma unroll
    for (int k3 = 0; k3 < 8; ++k3) v[k3] = w[k3];
}

// ---------- input dtype detection ----------
__global__ void detect_kernel(const unsigned int* __restrict__ words,
                              int* __restrict__ flag) {
    int t = threadIdx.x;
    unsigned long long m = __ballot((words[t] >> 15) & 1u);
    if (t == 0) *flag = (__popcll(m) > 16) ? 0 : 1;  // 0 = f32 input, 1 = bf16
}

// ---------- CIC paint: 16^3 core + halo2 ----------
// R4 version; launched as 2 x 256-block halves (base = 0, 256) so each paint
// dispatch is ~49us -> any other kernel >=50us becomes visible in top-5
// (attribution round; the halves are 1 block/CU so total stays ~98us).
__global__ __launch_bounds__(1024, 4)
void paint_lds(const void* __restrict__ pos, float* __restrict__ grid,
               const int* __restrict__ flag, int base) {
    __shared__ float tile[CELLS];
    int t = threadIdx.x;
    int bi = blockIdx.x + base;
    int tz = bi & 7, ty = (bi >> 3) & 7, tx = bi >> 6;
    int x0 = tx * 16, y0 = ty * 16, z0 = tz * 16;
    for (int i = t; i < CELLS; i += 1024) tile[i] = 0.f;
    int isbf16 = *flag;
    __syncthreads();

    int zg = t & 3, dy = (t >> 2) & 15, dx = t >> 6;
    int p0 = (((x0 + dx) << 7) + (y0 + dy)) * 128 + z0 + 4 * zg;

    float P[4][3];
    if (isbf16) {
        const uint2* q = (const uint2*)((const char*)pos + 6ll * p0);  // 24B, 8B-aligned
        uint2 a = q[0], b = q[1], c = q[2];
        unsigned int w[6] = {a.x, a.y, b.x, b.y, c.x, c.y};
#pragma unroll
        for (int e = 0; e < 12; ++e) {
            unsigned short h = (e & 1) ? (unsigned short)(w[e >> 1] >> 16)
                                       : (unsigned short)(w[e >> 1] & 0xffffu);
            P[e / 3][e % 3] = bf2f(h);
        }
    } else {
        const float4* q = (const float4*)((const float*)pos + 3ll * p0);  // 48B, 16B-aligned
        float4 a = q[0], b = q[1], c = q[2];
        P[0][0] = a.x; P[0][1] = a.y; P[0][2] = a.z;
        P[1][0] = a.w; P[1][1] = b.x; P[1][2] = b.y;
        P[2][0] = b.z; P[2][1] = b.w; P[2][2] = c.x;
        P[3][0] = c.y; P[3][1] = c.z; P[3][2] = c.w;
    }

#pragma unroll
    for (int it = 0; it < 4; ++it) {
        float P0 = P[it][0], P1 = P[it][1], P2 = P[it][2];
        float f0 = floorf(P0), f1 = floorf(P1), f2 = floorf(P2);
        int ix = (int)f0, iy = (int)f1, iz = (int)f2;
        float wx1 = P0 - f0, wy1 = P1 - f1, wz1 = P2 - f2;
        float wx0 = 1.f - wx1, wy0 = 1.f - wy1, wz0 = 1.f - wz1;
        int lx = (ix - x0 + 2) & 127, ly = (iy - y0 + 2) & 127;
        int lz = (iz - z0 + 2) & 127;
        if (lx <= 19 && ly <= 19 && lz <= 19) {
            int b00 = (lx * SP + ly) * SP + lz;
            int b01 = b00 + SP;
            int b10 = b00 + SP * SP;
            int b11 = b10 + SP;
            ldsAddF(&tile[b00],     wx0 * wy0 * wz0);
            ldsAddF(&tile[b00 + 1], wx0 * wy0 * wz1);
            ldsAddF(&tile[b01],     wx0 * wy1 * wz0);
            ldsAddF(&tile[b01 + 1], wx0 * wy1 * wz1);
            ldsAddF(&tile[b10],     wx1 * wy0 * wz0);
            ldsAddF(&tile[b10 + 1], wx1 * wy0 * wz1);
            ldsAddF(&tile[b11],     wx1 * wy1 * wz0);
            ldsAddF(&tile[b11 + 1], wx1 * wy1 * wz1);
        } else {  // rare outlier: global fallback
            int gx = ix & 127, gy = iy & 127, gz = iz & 127;
            int hx = (gx + 1) & 127, hy = (gy + 1) & 127, hz = (gz + 1) & 127;
            glbAddF(&grid[((gx << 7) + gy) * 128 + gz], wx0 * wy0 * wz0);
            glbAddF(&grid[((gx << 7) + gy) * 128 + hz], wx0 * wy0 * wz1);
            glbAddF(&grid[((gx << 7) + hy) * 128 + gz], wx0 * wy1 * wz0);
            glbAddF(&grid[((gx << 7) + hy) * 128 + hz], wx0 * wy1 * wz1);
            glbAddF(&grid[((hx << 7) + gy) * 128 + gz], wx1 * wy0 * wz0);
            glbAddF(&grid[((hx << 7) + gy) * 128 + hz], wx1 * wy0 * wz1);
            glbAddF(&grid[((hx << 7) + hy) * 128 + gz], wx1 * wy1 * wz0);
            glbAddF(&grid[((hx << 7) + hy) * 128 + hz], wx1 * wy1 * wz1);
        }
    }
    __syncthreads();
    for (int i = t; i < CELLS; i += 1024) {
        float v = tile[i];
        if (v != 0.f) {
            int lx = i / (SP * SP);
            int r  = i - lx * (SP * SP);
            int ly = r / SP, lz = r - ly * SP;
            int gx = (x0 - 2 + lx) & 127, gy = (y0 - 2 + ly) & 127;
            int gz = (z0 - 2 + lz) & 127;
            glbAddF(&grid[((gx << 7) + gy) * 128 + gz], v);
        }
    }
}

// ---------- fused forward z+y FFT: one x-plane per block, in LDS ----------
__global__ __launch_bounds__(1024)
void fft_zy_fwd(const float* __restrict__ delta, float2* __restrict__ A) {
    __shared__ float2 pl[128 * PSTR];   // 132 KB (gfx950 LDS = 160 KB/CU)
    int t = threadIdx.x, x = blockIdx.x;
    const float4* src = (const float4*)(delta + (long)x * MESH2);
    for (int i = t; i < MESH2 / 4; i += 1024) {
        float4 d = src[i];
        int y = i >> 5, z0 = (i & 31) * 4;
        float2* row = &pl[y * PSTR + z0];
        row[0] = make_float2(d.x, 0.f); row[1] = make_float2(d.y, 0.f);
        row[2] = make_float2(d.z, 0.f); row[3] = make_float2(d.w, 0.f);
    }
    __syncthreads();
    int u = t & 15, ln = t >> 4;            // 64 intra-wave line groups
    fft128_plane(pl, ln * PSTR, 1, u, -1.f);          // z-axis (rows)
    fft128_plane(pl, (ln + 64) * PSTR, 1, u, -1.f);
    __syncthreads();
    fft128_plane(pl, ln, PSTR, u, -1.f);              // y-axis (cols)
    fft128_plane(pl, ln + 64, PSTR, u, -1.f);
    __syncthreads();
    float4* dst = (float4*)(A + (long)x * MESH2);
    for (int i = t; i < MESH2 / 2; i += 1024) {
        int y = i >> 6, z0 = (i & 63) * 2;
        float2 e0 = pl[y * PSTR + z0], e1 = pl[y * PSTR + z0 + 1];
        dst[i] = make_float4(e0.x, e0.y, e1.x, e1.y);
    }
}

// ---------- fused x fwd-FFT + k-space kernel + x inv-FFT (both volumes) ----
__global__ __launch_bounds__(256)
void fft_x_fused(float2* __restrict__ A, float2* __restrict__ G2) {
    __shared__ float2 Z[16 * 137];
    int t = threadIdx.x;
    int l = t & 15, u = t >> 4;
    int L = blockIdx.x * 16 + l;
    const float invN3 = 1.0f / 2097152.0f;
    float2 X[8];
#pragma unroll
    for (int n1 = 0; n1 < 8; ++n1) X[n1] = A[(long)(16 * n1 + u) * MESH2 + L];
    fft128_Z(Z, l, u, -1.f, X);             // X[k3] = delta_k at kx = u+16*k3
    float ky = kfreq(L >> 7), kz = kfreq(L & 127);
    float2 g1[8], g2[8];
#pragma unroll
    for (int k3 = 0; k3 < 8; ++k3) {
        int k = u + 16 * k3;
        float kx = kfreq(k);
        float kk = kx * kx + ky * ky + kz * kz;
        float f = 0.f;
        if (kk > 0.f) f = -__expf(-0.09f / kk - kk * kk) / kk * invN3;
        float a = X[k3].x * f, b = X[k3].y * f;           // Pv
        g1[k3] = make_float2(-kx * b - ky * a, kx * a - ky * b);  // (ikx+i*iky)Pv
        g2[k3] = make_float2(-kz * b, kz * a);                    // ikz*Pv
    }
    fft128_Z(Z, l, u, 1.f, g1);
#pragma unroll
    for (int k3 = 0; k3 < 8; ++k3) A[(long)(u + 16 * k3) * MESH2 + L] = g1[k3];
    fft128_Z(Z, l, u, 1.f, g2);
#pragma unroll
    for (int k3 = 0; k3 < 8; ++k3) G2[(long)(u + 16 * k3) * MESH2 + L] = g2[k3];
}

// ---------- fused inverse y+z FFT + real extraction (grid 128 x 2 vols) ----
__global__ __launch_bounds__(1024)
void fft_yz_inv(const float2* __restrict__ G1, const float2* __restrict__ G2,
                float* __restrict__ F0, float* __restrict__ F1,
                float* __restrict__ F2) {
    __shared__ float2 pl[128 * PSTR];
    int t = threadIdx.x, x = blockIdx.x, vol = blockIdx.y;
    const float4* src = (const float4*)((vol ? G2 : G1) + (long)x * MESH2);
    for (int i = t; i < MESH2 / 2; i += 1024) {
        float4 d = src[i];
        int y = i >> 6, z0 = (i & 63) * 2;
        pl[y * PSTR + z0]     = make_float2(d.x, d.y);
        pl[y * PSTR + z0 + 1] = make_float2(d.z, d.w);
    }
    __syncthreads();
    int u = t & 15, ln = t >> 4;
    fft128_plane(pl, ln * PSTR, 1, u, 1.f);           // z-axis
    fft128_plane(pl, (ln + 64) * PSTR, 1, u, 1.f);
    __syncthreads();
    fft128_plane(pl, ln, PSTR, u, 1.f);               // y-axis
    fft128_plane(pl, ln + 64, PSTR, u, 1.f);
    __syncthreads();
    long b = (long)x * MESH2;
    if (vol == 0) {
        for (int i = t; i < MESH2; i += 1024) {
            float2 v = pl[(i >> 7) * PSTR + (i & 127)];
            F0[b + i] = v.x;   // Fx
            F1[b + i] = v.y;   // Fy
        }
    } else {
        for (int i = t; i < MESH2; i += 1024)
            F2[b + i] = pl[(i >> 7) * PSTR + (i & 127)].x;   // Fz
    }
}

// ---------- CIC read + position update (writes pos half [0,24Mi) ONLY) ----------
__global__ __launch_bounds__(256)
void update_pos(const void* __restrict__ pos,
                const float* __restrict__ Fx, const float* __restrict__ Fy,
                const float* __restrict__ Fz, float* __restrict__ out,
                const int* __restrict__ flag, int n) {
    int p = blockIdx.x * blockDim.x + threadIdx.x;
    if (p >= n) return;
    int isbf16 = *flag;
    float P0 = load_elem(pos, 3 * p + 0, isbf16);
    float P1 = load_elem(pos, 3 * p + 1, isbf16);
    float P2 = load_elem(pos, 3 * p + 2, isbf16);
    float f0 = floorf(P0), f1 = floorf(P1), f2 = floorf(P2);
    int ix = ((int)f0) & 127, iy = ((int)f1) & 127, iz = ((int)f2) & 127;
    float wx1 = P0 - f0, wy1 = P1 - f1, wz1 = P2 - f2;
    float wx0 = 1.f - wx1, wy0 = 1.f - wy1, wz0 = 1.f - wz1;
    int jx = (ix + 1) & 127, jy = (iy + 1) & 127, jz = (iz + 1) & 127;
    int b00 = (ix * MESH + iy) * MESH;
    int b01 = (ix * MESH + jy) * MESH;
    int b10 = (jx * MESH + iy) * MESH;
    int b11 = (jx * MESH + jy) * MESH;
    float fx = 0.f, fy = 0.f, fz = 0.f;
    int f; float w;
    f = b00 + iz; w = wx0 * wy0 * wz0; fx += w * Fx[f]; fy += w * Fy[f]; fz += w * Fz[f];
    f = b00 + jz; w = wx0 * wy0 * wz1; fx += w * Fx[f]; fy += w * Fy[f]; fz += w * Fz[f];
    f = b01 + iz; w = wx0 * wy1 * wz0; fx += w * Fx[f]; fy += w * Fy[f]; fz += w * Fz[f];
    f = b01 + jz; w = wx0 * wy1 * wz1; fx += w * Fx[f]; fy += w * Fy[f]; fz += w * Fz[f];
    f = b10 + iz; w = wx1 * wy0 * wz0; fx += w * Fx[f]; fy += w * Fy[f]; fz += w * Fz[f];
    f = b10 + jz; w = wx1 * wy0 * wz1; fx += w * Fx[f]; fy += w * Fy[f]; fz += w * Fz[f];
    f = b11 + iz; w = wx1 * wy1 * wz0; fx += w * Fx[f]; fy += w * Fy[f]; fz += w * Fz[f];
    f = b11 + jz; w = wx1 * wy1 * wz1; fx += w * Fx[f]; fy += w * Fy[f]; fz += w * Fz[f];
    out[3 * p + 0] = P0 + 0.2f * fx;
    out[3 * p + 1] = P1 + 0.2f * fy;
    out[3 * p + 2] = P2 + 0.2f * fz;
}

// ---------- vel passthrough (second half of out; runs AFTER update_pos) ----------
__global__ __launch_bounds__(256)
void copy_vel(const void* __restrict__ vel, float* __restrict__ dst,
              const int* __restrict__ flag, int m) {   // m = 3n floats
    int i0 = (blockIdx.x * blockDim.x + threadIdx.x) * 4;
    int isbf16 = *flag;
#pragma unroll
    for (int j = 0; j < 4; ++j) {
        int i = i0 + j;
        if (i < m) dst[i] = load_elem(vel, i, isbf16);
    }
}

// ---------- launch ----------
// ws (32Mi+4K): [0,4K) flag | A @ [4K,16Mi+4K) | F0 @ +16Mi | F1 @ +24Mi.
// d_out (48Mi): delta @ [0,8Mi) | G2 @ [24Mi,40Mi) | F2 @ [40Mi,48Mi).
extern "C" void kernel_launch(void* const* d_in, const int* in_sizes, int n_in,
                              void* d_out, int out_size, void* d_ws, size_t ws_size,
                              hipStream_t stream) {
    int n = in_sizes[0] / 3;
    const void* pos = d_in[0];
    const void* vel = d_in[1];
    float* out = (float*)d_out;

    char* ws = (char*)d_ws;
    int*    flag = (int*)ws;
    float2* A  = (float2*)(ws + 4096);
    float*  F0 = (float*)(ws + 4096 + (16u << 20));
    float*  F1 = (float*)(ws + 4096 + (24u << 20));
    float*  delta = (float*)d_out;                           // [0, 8Mi)
    float2* G2 = (float2*)((char*)d_out + (24u << 20));      // [24Mi, 40Mi)
    float*  F2 = (float*)((char*)d_out + (40u << 20));       // [40Mi, 48Mi)

    detect_kernel<<<1, 64, 0, stream>>>((const unsigned int*)pos, flag);
    hipMemsetAsync(delta, 0, MESH3 * sizeof(float), stream);
    paint_lds<<<256, 1024, 0, stream>>>(pos, delta, flag, 0);
    paint_lds<<<256, 1024, 0, stream>>>(pos, delta, flag, 256);

    fft_zy_fwd<<<128, 1024, 0, stream>>>(delta, A);
    fft_x_fused<<<1024, 256, 0, stream>>>(A, G2);
    fft_yz_inv<<<dim3(128, 2), 1024, 0, stream>>>(A, G2, F0, F1, F2);

    update_pos<<<(n + 255) / 256, 256, 0, stream>>>(pos, F0, F1, F2, out, flag, n);
    int m = 3 * n;
    copy_vel<<<(m / 4 + 255) / 256, 256, 0, stream>>>(vel, out + m, flag, m);
}

// Round 13
// 283.752 us; speedup vs baseline: 1.0725x; 1.0725x over previous
//
#include <hip/hip_runtime.h>
#include <hip/hip_bf16.h>

#define MESH   128
#define MESH2  16384
#define MESH3  2097152
// paint tile: 16x16x16 core, halo 2 each side -> span 21 per axis
#define SP 21
#define CELLS (SP * SP * SP)   // 9261 floats = 36.2 KB
#define PSTR 129               // LDS plane row stride (float2): bank-conflict pad

// ---------- helpers ----------
__device__ __forceinline__ float kfreq(int i) {
    int s = (i < 64) ? i : (i - 128);
    return 0.049087385212340517f * (float)s;   // 2*pi*fftfreq(128)[i]
}

__device__ __forceinline__ float load_elem(const void* p, int i, int isbf16) {
    if (isbf16) return __bfloat162float(((const __hip_bfloat16*)p)[i]);
    return ((const float*)p)[i];
}

__device__ __forceinline__ float bf2f(unsigned short u) {
    unsigned int w = ((unsigned int)u) << 16;
    return __uint_as_float(w);
}

// Native FP atomics via inline asm (paint sits at the LDS atomic-RMW floor;
// proven invariant across R0-R6).
__device__ __forceinline__ void ldsAddF(float* p, float v) {
    unsigned off = (unsigned)(unsigned long long)p;
    asm volatile("ds_add_f32 %0, %1" :: "v"(off), "v"(v) : "memory");
}
__device__ __forceinline__ void glbAddF(float* p, float v) {
    asm volatile("global_atomic_add_f32 %0, %1, off" :: "v"(p), "v"(v) : "memory");
}

// 8-point DFT in registers, natural order, e^{sgn*2pi*i*nk/8}
__device__ __forceinline__ void dft8(float2* a, float sgn) {
    const float r = 0.70710678118654752f;
    float2 b0 = a[0], b1 = a[4], b2 = a[2], b3 = a[6];
    float2 b4 = a[1], b5 = a[5], b6 = a[3], b7 = a[7];
    float2 c0 = make_float2(b0.x + b1.x, b0.y + b1.y);
    float2 c1 = make_float2(b0.x - b1.x, b0.y - b1.y);
    float2 c2 = make_float2(b2.x + b3.x, b2.y + b3.y);
    float2 c3 = make_float2(b2.x - b3.x, b2.y - b3.y);
    float2 c4 = make_float2(b4.x + b5.x, b4.y + b5.y);
    float2 c5 = make_float2(b4.x - b5.x, b4.y - b5.y);
    float2 c6 = make_float2(b6.x + b7.x, b6.y + b7.y);
    float2 c7 = make_float2(b6.x - b7.x, b6.y - b7.y);
    float2 t3 = make_float2(-sgn * c3.y, sgn * c3.x);
    float2 t7 = make_float2(-sgn * c7.y, sgn * c7.x);
    float2 d0 = make_float2(c0.x + c2.x, c0.y + c2.y);
    float2 d2 = make_float2(c0.x - c2.x, c0.y - c2.y);
    float2 d1 = make_float2(c1.x + t3.x, c1.y + t3.y);
    float2 d3 = make_float2(c1.x - t3.x, c1.y - t3.y);
    float2 d4 = make_float2(c4.x + c6.x, c4.y + c6.y);
    float2 d6 = make_float2(c4.x - c6.x, c4.y - c6.y);
    float2 d5 = make_float2(c5.x + t7.x, c5.y + t7.y);
    float2 d7 = make_float2(c5.x - t7.x, c5.y - t7.y);
    float2 w1 = make_float2(r, sgn * r), w3 = make_float2(-r, sgn * r);
    float2 t5 = make_float2(d5.x * w1.x - d5.y * w1.y, d5.x * w1.y + d5.y * w1.x);
    float2 t6 = make_float2(-sgn * d6.y, sgn * d6.x);
    float2 t7b = make_float2(d7.x * w3.x - d7.y * w3.y, d7.x * w3.y + d7.y * w3.x);
    a[0] = make_float2(d0.x + d4.x, d0.y + d4.y);
    a[4] = make_float2(d0.x - d4.x, d0.y - d4.y);
    a[1] = make_float2(d1.x + t5.x, d1.y + t5.y);
    a[5] = make_float2(d1.x - t5.x, d1.y - t5.y);
    a[2] = make_float2(d2.x + t6.x, d2.y + t6.y);
    a[6] = make_float2(d2.x - t6.x, d2.y - t6.y);
    a[3] = make_float2(d3.x + t7b.x, d3.y + t7b.y);
    a[7] = make_float2(d3.x - t7b.x, d3.y - t7b.y);
}

// ---------- register twiddle cache ----------
// tw1[k1] = exp(-2*pi*i*u*k1/128)  (depends only on the thread's fixed u)
// tw2[b]  = exp(-2*pi*i*b/16)      (universal)
// Forward transform: tsgn=+1. Inverse: conjugate -> tsgn=-1 (sn negated).
// Computed ONCE per thread (16 sincos) and reused across all fft128 calls
// (previously ~15 sincos per call x 3-4 calls).
__device__ __forceinline__ void make_twiddles(int u, float2* tw1, float2* tw2) {
#pragma unroll
    for (int k = 0; k < 8; ++k) {
        float sn, cs;
        __sincosf(-0.049087385212340517f * (float)(u * k), &sn, &cs);
        tw1[k] = make_float2(cs, sn);
    }
#pragma unroll
    for (int b = 0; b < 8; ++b) {
        float sn, cs;
        __sincosf(-0.39269908169872414f * (float)b, &sn, &cs);
        tw2[b] = make_float2(cs, sn);
    }
}

// ---------- 128-pt radix-8x16 FFT on an LDS plane line (in-place) ----------
// Line owned by ONE 16-lane intra-wave group (u = lane&15): the two-stage
// exchange goes through the line's own 128 slots with a rotated mapping
// slot(k1,j) = k1*16 + ((j + 2*k1) & 15)  (bijective per k1; bank-spread).
// Same-wave LDS ops are in-order -> no barriers needed.
__device__ __forceinline__ void fft128_plane(float2* pl, int lb, int stride,
                                             int u, float sgn, float tsgn,
                                             const float2* tw1,
                                             const float2* tw2) {
    float2 v[8];
#pragma unroll
    for (int n1 = 0; n1 < 8; ++n1) v[n1] = pl[lb + (16 * n1 + u) * stride];
    dft8(v, sgn);
#pragma unroll
    for (int k1 = 0; k1 < 8; ++k1) {
        float cs = tw1[k1].x, sn = tw1[k1].y * tsgn;
        float2 y = v[k1];
        int slot = k1 * 16 + ((u + 2 * k1) & 15);
        pl[lb + slot * stride] = make_float2(y.x * cs - y.y * sn, y.x * sn + y.y * cs);
    }
    asm volatile("" ::: "memory");   // keep LDS write->read order at compile level
    int k1 = u & 7, c = u >> 3;
    float2 w[8];
#pragma unroll
    for (int b = 0; b < 8; ++b) {
        float2 za = pl[lb + (k1 * 16 + ((b + 2 * k1) & 15)) * stride];
        float2 zb = pl[lb + (k1 * 16 + ((8 + b + 2 * k1) & 15)) * stride];
        float2 s = c ? make_float2(za.x - zb.x, za.y - zb.y)
                     : make_float2(za.x + zb.x, za.y + zb.y);
        if (c && b) {
            float cs = tw2[b].x, sn = tw2[b].y * tsgn;
            s = make_float2(s.x * cs - s.y * sn, s.x * sn + s.y * cs);
        }
        w[b] = s;
    }
    dft8(w, sgn);
    asm volatile("" ::: "memory");
#pragma unroll
    for (int k3 = 0; k3 < 8; ++k3) pl[lb + (u + 16 * k3) * stride] = w[k3];
}

// ---------- 128-pt FFT through a block-shared Z buffer (lines span waves) ----
// Thread (l,u): v[n1] = elem[16*n1+u] in, v[k3] = elem[u+16*k3] out.
// Leading __syncthreads makes Z reusable across consecutive calls.
__device__ __forceinline__ void fft128_Z(float2* Z, int l, int u, float sgn,
                                         float tsgn, const float2* tw1,
                                         const float2* tw2, float2* v) {
    __syncthreads();
    dft8(v, sgn);
#pragma unroll
    for (int k1 = 0; k1 < 8; ++k1) {
        float cs = tw1[k1].x, sn = tw1[k1].y * tsgn;
        float2 y = v[k1];
        Z[l * 137 + k1 * 17 + u] = make_float2(y.x * cs - y.y * sn, y.x * sn + y.y * cs);
    }
    __syncthreads();
    int k1 = u & 7, c = u >> 3;
    float2 w[8];
#pragma unroll
    for (int b = 0; b < 8; ++b) {
        float2 za = Z[l * 137 + k1 * 17 + b];
        float2 zb = Z[l * 137 + k1 * 17 + 8 + b];
        float2 s = c ? make_float2(za.x - zb.x, za.y - zb.y)
                     : make_float2(za.x + zb.x, za.y + zb.y);
        if (c && b) {
            float cs = tw2[b].x, sn = tw2[b].y * tsgn;
            s = make_float2(s.x * cs - s.y * sn, s.x * sn + s.y * cs);
        }
        w[b] = s;
    }
    dft8(w, sgn);
#pragma unroll
    for (int k3 = 0; k3 < 8; ++k3) v[k3] = w[k3];
}

// ---------- input dtype detection ----------
__global__ void detect_kernel(const unsigned int* __restrict__ words,
                              int* __restrict__ flag) {
    int t = threadIdx.x;
    unsigned long long m = __ballot((words[t] >> 15) & 1u);
    if (t == 0) *flag = (__popcll(m) > 16) ? 0 : 1;  // 0 = f32 input, 1 = bf16
}

// ---------- CIC paint: 16^3 core + halo2 (512 blocks x 1024 threads) ----------
// R4 version, single launch (R12's 2x256 split cost +15us: the halves ran
// 56.5us each, so co-resident blocks DO partially overlap). LDS-atomic floor.
__global__ __launch_bounds__(1024, 4)
void paint_lds(const void* __restrict__ pos, float* __restrict__ grid,
               const int* __restrict__ flag) {
    __shared__ float tile[CELLS];
    int t = threadIdx.x;
    int bi = blockIdx.x;
    int tz = bi & 7, ty = (bi >> 3) & 7, tx = bi >> 6;
    int x0 = tx * 16, y0 = ty * 16, z0 = tz * 16;
    for (int i = t; i < CELLS; i += 1024) tile[i] = 0.f;
    int isbf16 = *flag;
    __syncthreads();

    int zg = t & 3, dy = (t >> 2) & 15, dx = t >> 6;
    int p0 = (((x0 + dx) << 7) + (y0 + dy)) * 128 + z0 + 4 * zg;

    float P[4][3];
    if (isbf16) {
        const uint2* q = (const uint2*)((const char*)pos + 6ll * p0);  // 24B, 8B-aligned
        uint2 a = q[0], b = q[1], c = q[2];
        unsigned int w[6] = {a.x, a.y, b.x, b.y, c.x, c.y};
#pragma unroll
        for (int e = 0; e < 12; ++e) {
            unsigned short h = (e & 1) ? (unsigned short)(w[e >> 1] >> 16)
                                       : (unsigned short)(w[e >> 1] & 0xffffu);
            P[e / 3][e % 3] = bf2f(h);
        }
    } else {
        const float4* q = (const float4*)((const float*)pos + 3ll * p0);  // 48B, 16B-aligned
        float4 a = q[0], b = q[1], c = q[2];
        P[0][0] = a.x; P[0][1] = a.y; P[0][2] = a.z;
        P[1][0] = a.w; P[1][1] = b.x; P[1][2] = b.y;
        P[2][0] = b.z; P[2][1] = b.w; P[2][2] = c.x;
        P[3][0] = c.y; P[3][1] = c.z; P[3][2] = c.w;
    }

#pragma unroll
    for (int it = 0; it < 4; ++it) {
        float P0 = P[it][0], P1 = P[it][1], P2 = P[it][2];
        float f0 = floorf(P0), f1 = floorf(P1), f2 = floorf(P2);
        int ix = (int)f0, iy = (int)f1, iz = (int)f2;
        float wx1 = P0 - f0, wy1 = P1 - f1, wz1 = P2 - f2;
        float wx0 = 1.f - wx1, wy0 = 1.f - wy1, wz0 = 1.f - wz1;
        int lx = (ix - x0 + 2) & 127, ly = (iy - y0 + 2) & 127;
        int lz = (iz - z0 + 2) & 127;
        if (lx <= 19 && ly <= 19 && lz <= 19) {
            int b00 = (lx * SP + ly) * SP + lz;
            int b01 = b00 + SP;
            int b10 = b00 + SP * SP;
            int b11 = b10 + SP;
            ldsAddF(&tile[b00],     wx0 * wy0 * wz0);
            ldsAddF(&tile[b00 + 1], wx0 * wy0 * wz1);
            ldsAddF(&tile[b01],     wx0 * wy1 * wz0);
            ldsAddF(&tile[b01 + 1], wx0 * wy1 * wz1);
            ldsAddF(&tile[b10],     wx1 * wy0 * wz0);
            ldsAddF(&tile[b10 + 1], wx1 * wy0 * wz1);
            ldsAddF(&tile[b11],     wx1 * wy1 * wz0);
            ldsAddF(&tile[b11 + 1], wx1 * wy1 * wz1);
        } else {  // rare outlier: global fallback
            int gx = ix & 127, gy = iy & 127, gz = iz & 127;
            int hx = (gx + 1) & 127, hy = (gy + 1) & 127, hz = (gz + 1) & 127;
            glbAddF(&grid[((gx << 7) + gy) * 128 + gz], wx0 * wy0 * wz0);
            glbAddF(&grid[((gx << 7) + gy) * 128 + hz], wx0 * wy0 * wz1);
            glbAddF(&grid[((gx << 7) + hy) * 128 + gz], wx0 * wy1 * wz0);
            glbAddF(&grid[((gx << 7) + hy) * 128 + hz], wx0 * wy1 * wz1);
            glbAddF(&grid[((hx << 7) + gy) * 128 + gz], wx1 * wy0 * wz0);
            glbAddF(&grid[((hx << 7) + gy) * 128 + hz], wx1 * wy0 * wz1);
            glbAddF(&grid[((hx << 7) + hy) * 128 + gz], wx1 * wy1 * wz0);
            glbAddF(&grid[((hx << 7) + hy) * 128 + hz], wx1 * wy1 * wz1);
        }
    }
    __syncthreads();
    for (int i = t; i < CELLS; i += 1024) {
        float v = tile[i];
        if (v != 0.f) {
            int lx = i / (SP * SP);
            int r  = i - lx * (SP * SP);
            int ly = r / SP, lz = r - ly * SP;
            int gx = (x0 - 2 + lx) & 127, gy = (y0 - 2 + ly) & 127;
            int gz = (z0 - 2 + lz) & 127;
            glbAddF(&grid[((gx << 7) + gy) * 128 + gz], v);
        }
    }
}

// ---------- fused forward z+y FFT: one x-plane per block, in LDS ----------
__global__ __launch_bounds__(1024)
void fft_zy_fwd(const float* __restrict__ delta, float2* __restrict__ A) {
    __shared__ float2 pl[128 * PSTR];   // 132 KB (gfx950 LDS = 160 KB/CU)
    int t = threadIdx.x, x = blockIdx.x;
    const float4* src = (const float4*)(delta + (long)x * MESH2);
    for (int i = t; i < MESH2 / 4; i += 1024) {
        float4 d = src[i];
        int y = i >> 5, z0 = (i & 31) * 4;
        float2* row = &pl[y * PSTR + z0];
        row[0] = make_float2(d.x, 0.f); row[1] = make_float2(d.y, 0.f);
        row[2] = make_float2(d.z, 0.f); row[3] = make_float2(d.w, 0.f);
    }
    int u = t & 15, ln = t >> 4;            // 64 intra-wave line groups
    float2 tw1[8], tw2[8];
    make_twiddles(u, tw1, tw2);
    __syncthreads();
    fft128_plane(pl, ln * PSTR, 1, u, -1.f, 1.f, tw1, tw2);        // z-axis
    fft128_plane(pl, (ln + 64) * PSTR, 1, u, -1.f, 1.f, tw1, tw2);
    __syncthreads();
    fft128_plane(pl, ln, PSTR, u, -1.f, 1.f, tw1, tw2);            // y-axis
    fft128_plane(pl, ln + 64, PSTR, u, -1.f, 1.f, tw1, tw2);
    __syncthreads();
    float4* dst = (float4*)(A + (long)x * MESH2);
    for (int i = t; i < MESH2 / 2; i += 1024) {
        int y = i >> 6, z0 = (i & 63) * 2;
        float2 e0 = pl[y * PSTR + z0], e1 = pl[y * PSTR + z0 + 1];
        dst[i] = make_float4(e0.x, e0.y, e1.x, e1.y);
    }
}

// ---------- fused x fwd-FFT + k-space kernel + x inv-FFT (both volumes) ----
__global__ __launch_bounds__(256)
void fft_x_fused(float2* __restrict__ A, float2* __restrict__ G2) {
    __shared__ float2 Z[16 * 137];
    int t = threadIdx.x;
    int l = t & 15, u = t >> 4;
    int L = blockIdx.x * 16 + l;
    const float invN3 = 1.0f / 2097152.0f;
    float2 tw1[8], tw2[8];
    make_twiddles(u, tw1, tw2);
    float2 X[8];
#pragma unroll
    for (int n1 = 0; n1 < 8; ++n1) X[n1] = A[(long)(16 * n1 + u) * MESH2 + L];
    fft128_Z(Z, l, u, -1.f, 1.f, tw1, tw2, X);   // X[k3] = delta_k at kx=u+16*k3
    float ky = kfreq(L >> 7), kz = kfreq(L & 127);
    float2 g1[8], g2[8];
#pragma unroll
    for (int k3 = 0; k3 < 8; ++k3) {
        int k = u + 16 * k3;
        float kx = kfreq(k);
        float kk = kx * kx + ky * ky + kz * kz;
        float f = 0.f;
        if (kk > 0.f) f = -__expf(-0.09f / kk - kk * kk) / kk * invN3;
        float a = X[k3].x * f, b = X[k3].y * f;           // Pv
        g1[k3] = make_float2(-kx * b - ky * a, kx * a - ky * b);  // (ikx+i*iky)Pv
        g2[k3] = make_float2(-kz * b, kz * a);                    // ikz*Pv
    }
    fft128_Z(Z, l, u, 1.f, -1.f, tw1, tw2, g1);   // inverse: conj twiddles
#pragma unroll
    for (int k3 = 0; k3 < 8; ++k3) A[(long)(u + 16 * k3) * MESH2 + L] = g1[k3];
    fft128_Z(Z, l, u, 1.f, -1.f, tw1, tw2, g2);
#pragma unroll
    for (int k3 = 0; k3 < 8; ++k3) G2[(long)(u + 16 * k3) * MESH2 + L] = g2[k3];
}

// ---------- fused inverse y+z FFT + real extraction (grid 128 x 2 vols) ----
__global__ __launch_bounds__(1024)
void fft_yz_inv(const float2* __restrict__ G1, const float2* __restrict__ G2,
                float* __restrict__ F0, float* __restrict__ F1,
                float* __restrict__ F2) {
    __shared__ float2 pl[128 * PSTR];
    int t = threadIdx.x, x = blockIdx.x, vol = blockIdx.y;
    const float4* src = (const float4*)((vol ? G2 : G1) + (long)x * MESH2);
    for (int i = t; i < MESH2 / 2; i += 1024) {
        float4 d = src[i];
        int y = i >> 6, z0 = (i & 63) * 2;
        pl[y * PSTR + z0]     = make_float2(d.x, d.y);
        pl[y * PSTR + z0 + 1] = make_float2(d.z, d.w);
    }
    int u = t & 15, ln = t >> 4;
    float2 tw1[8], tw2[8];
    make_twiddles(u, tw1, tw2);
    __syncthreads();
    fft128_plane(pl, ln * PSTR, 1, u, 1.f, -1.f, tw1, tw2);        // z-axis
    fft128_plane(pl, (ln + 64) * PSTR, 1, u, 1.f, -1.f, tw1, tw2);
    __syncthreads();
    fft128_plane(pl, ln, PSTR, u, 1.f, -1.f, tw1, tw2);            // y-axis
    fft128_plane(pl, ln + 64, PSTR, u, 1.f, -1.f, tw1, tw2);
    __syncthreads();
    long b = (long)x * MESH2;
    if (vol == 0) {
        for (int i = t; i < MESH2; i += 1024) {
            float2 v = pl[(i >> 7) * PSTR + (i & 127)];
            F0[b + i] = v.x;   // Fx
            F1[b + i] = v.y;   // Fy
        }
    } else {
        for (int i = t; i < MESH2; i += 1024)
            F2[b + i] = pl[(i >> 7) * PSTR + (i & 127)].x;   // Fz
    }
}

// ---------- CIC read + position update (writes pos half [0,24Mi) ONLY) ----------
__global__ __launch_bounds__(256)
void update_pos(const void* __restrict__ pos,
                const float* __restrict__ Fx, const float* __restrict__ Fy,
                const float* __restrict__ Fz, float* __restrict__ out,
                const int* __restrict__ flag, int n) {
    int p = blockIdx.x * blockDim.x + threadIdx.x;
    if (p >= n) return;
    int isbf16 = *flag;
    float P0 = load_elem(pos, 3 * p + 0, isbf16);
    float P1 = load_elem(pos, 3 * p + 1, isbf16);
    float P2 = load_elem(pos, 3 * p + 2, isbf16);
    float f0 = floorf(P0), f1 = floorf(P1), f2 = floorf(P2);
    int ix = ((int)f0) & 127, iy = ((int)f1) & 127, iz = ((int)f2) & 127;
    float wx1 = P0 - f0, wy1 = P1 - f1, wz1 = P2 - f2;
    float wx0 = 1.f - wx1, wy0 = 1.f - wy1, wz0 = 1.f - wz1;
    int jx = (ix + 1) & 127, jy = (iy + 1) & 127, jz = (iz + 1) & 127;
    int b00 = (ix * MESH + iy) * MESH;
    int b01 = (ix * MESH + jy) * MESH;
    int b10 = (jx * MESH + iy) * MESH;
    int b11 = (jx * MESH + jy) * MESH;
    float fx = 0.f, fy = 0.f, fz = 0.f;
    int f; float w;
    f = b00 + iz; w = wx0 * wy0 * wz0; fx += w * Fx[f]; fy += w * Fy[f]; fz += w * Fz[f];
    f = b00 + jz; w = wx0 * wy0 * wz1; fx += w * Fx[f]; fy += w * Fy[f]; fz += w * Fz[f];
    f = b01 + iz; w = wx0 * wy1 * wz0; fx += w * Fx[f]; fy += w * Fy[f]; fz += w * Fz[f];
    f = b01 + jz; w = wx0 * wy1 * wz1; fx += w * Fx[f]; fy += w * Fy[f]; fz += w * Fz[f];
    f = b10 + iz; w = wx1 * wy0 * wz0; fx += w * Fx[f]; fy += w * Fy[f]; fz += w * Fz[f];
    f = b10 + jz; w = wx1 * wy0 * wz1; fx += w * Fx[f]; fy += w * Fy[f]; fz += w * Fz[f];
    f = b11 + iz; w = wx1 * wy1 * wz0; fx += w * Fx[f]; fy += w * Fy[f]; fz += w * Fz[f];
    f = b11 + jz; w = wx1 * wy1 * wz1; fx += w * Fx[f]; fy += w * Fy[f]; fz += w * Fz[f];
    out[3 * p + 0] = P0 + 0.2f * fx;
    out[3 * p + 1] = P1 + 0.2f * fy;
    out[3 * p + 2] = P2 + 0.2f * fz;
}

// ---------- vel passthrough (second half of out; runs AFTER update_pos) ----------
// Vectorized: one float4 store (and one float4/uint2 load) per thread.
// m = 3n is divisible by 4 (n = 2^21); bases are 16B-aligned.
__global__ __launch_bounds__(256)
void copy_vel(const void* __restrict__ vel, float* __restrict__ dst,
              const int* __restrict__ flag, int m) {   // m = 3n floats
    int i0 = (blockIdx.x * blockDim.x + threadIdx.x) * 4;
    if (i0 >= m) return;
    if (*flag) {  // bf16: 4 elems = 8 B
        uint2 w = *(const uint2*)((const char*)vel + (size_t)i0 * 2);
        *(float4*)(dst + i0) = make_float4(
            bf2f((unsigned short)(w.x & 0xffffu)), bf2f((unsigned short)(w.x >> 16)),
            bf2f((unsigned short)(w.y & 0xffffu)), bf2f((unsigned short)(w.y >> 16)));
    } else {      // f32: 16 B
        *(float4*)(dst + i0) = *(const float4*)((const float*)vel + i0);
    }
}

// ---------- launch ----------
// ws (32Mi+4K): [0,4K) flag | A @ [4K,16Mi+4K) | F0 @ +16Mi | F1 @ +24Mi.
// d_out (48Mi): delta @ [0,8Mi) | G2 @ [24Mi,40Mi) | F2 @ [40Mi,48Mi).
extern "C" void kernel_launch(void* const* d_in, const int* in_sizes, int n_in,
                              void* d_out, int out_size, void* d_ws, size_t ws_size,
                              hipStream_t stream) {
    int n = in_sizes[0] / 3;
    const void* pos = d_in[0];
    const void* vel = d_in[1];
    float* out = (float*)d_out;

    char* ws = (char*)d_ws;
    int*    flag = (int*)ws;
    float2* A  = (float2*)(ws + 4096);
    float*  F0 = (float*)(ws + 4096 + (16u << 20));
    float*  F1 = (float*)(ws + 4096 + (24u << 20));
    float*  delta = (float*)d_out;                           // [0, 8Mi)
    float2* G2 = (float2*)((char*)d_out + (24u << 20));      // [24Mi, 40Mi)
    float*  F2 = (float*)((char*)d_out + (40u << 20));       // [40Mi, 48Mi)

    detect_kernel<<<1, 64, 0, stream>>>((const unsigned int*)pos, flag);
    hipMemsetAsync(delta, 0, MESH3 * sizeof(float), stream);
    paint_lds<<<512, 1024, 0, stream>>>(pos, delta, flag);

    fft_zy_fwd<<<128, 1024, 0, stream>>>(delta, A);
    fft_x_fused<<<1024, 256, 0, stream>>>(A, G2);
    fft_yz_inv<<<dim3(128, 2), 1024, 0, stream>>>(A, G2, F0, F1, F2);

    update_pos<<<(n + 255) / 256, 256, 0, stream>>>(pos, F0, F1, F2, out, flag, n);
    int m = 3 * n;
    copy_vel<<<(m / 4 + 255) / 256, 256, 0, stream>>>(vel, out + m, flag, m);
}

// Round 14
// 281.513 us; speedup vs baseline: 1.0811x; 1.0080x over previous
//
#include <hip/hip_runtime.h>
#include <hip/hip_bf16.h>

#define MESH   128
#define MESH2  16384
#define MESH3  2097152
// paint tile: 16x16x16 core, halo 2 each side -> span 21 per axis
#define SP 21
#define CELLS (SP * SP * SP)   // 9261 floats = 36.2 KB
#define PSTR 129               // LDS plane row stride (float2): bank-conflict pad

// ---------- helpers ----------
__device__ __forceinline__ float kfreq(int i) {
    int s = (i < 64) ? i : (i - 128);
    return 0.049087385212340517f * (float)s;   // 2*pi*fftfreq(128)[i]
}

__device__ __forceinline__ float load_elem(const void* p, int i, int isbf16) {
    if (isbf16) return __bfloat162float(((const __hip_bfloat16*)p)[i]);
    return ((const float*)p)[i];
}

__device__ __forceinline__ float bf2f(unsigned short u) {
    unsigned int w = ((unsigned int)u) << 16;
    return __uint_as_float(w);
}

// Native FP atomics via inline asm (paint sits at the LDS atomic-RMW floor;
// proven invariant across R0-R6).
__device__ __forceinline__ void ldsAddF(float* p, float v) {
    unsigned off = (unsigned)(unsigned long long)p;
    asm volatile("ds_add_f32 %0, %1" :: "v"(off), "v"(v) : "memory");
}
__device__ __forceinline__ void glbAddF(float* p, float v) {
    asm volatile("global_atomic_add_f32 %0, %1, off" :: "v"(p), "v"(v) : "memory");
}

// 8-point DFT in registers, natural order, e^{sgn*2pi*i*nk/8}
__device__ __forceinline__ void dft8(float2* a, float sgn) {
    const float r = 0.70710678118654752f;
    float2 b0 = a[0], b1 = a[4], b2 = a[2], b3 = a[6];
    float2 b4 = a[1], b5 = a[5], b6 = a[3], b7 = a[7];
    float2 c0 = make_float2(b0.x + b1.x, b0.y + b1.y);
    float2 c1 = make_float2(b0.x - b1.x, b0.y - b1.y);
    float2 c2 = make_float2(b2.x + b3.x, b2.y + b3.y);
    float2 c3 = make_float2(b2.x - b3.x, b2.y - b3.y);
    float2 c4 = make_float2(b4.x + b5.x, b4.y + b5.y);
    float2 c5 = make_float2(b4.x - b5.x, b4.y - b5.y);
    float2 c6 = make_float2(b6.x + b7.x, b6.y + b7.y);
    float2 c7 = make_float2(b6.x - b7.x, b6.y - b7.y);
    float2 t3 = make_float2(-sgn * c3.y, sgn * c3.x);
    float2 t7 = make_float2(-sgn * c7.y, sgn * c7.x);
    float2 d0 = make_float2(c0.x + c2.x, c0.y + c2.y);
    float2 d2 = make_float2(c0.x - c2.x, c0.y - c2.y);
    float2 d1 = make_float2(c1.x + t3.x, c1.y + t3.y);
    float2 d3 = make_float2(c1.x - t3.x, c1.y - t3.y);
    float2 d4 = make_float2(c4.x + c6.x, c4.y + c6.y);
    float2 d6 = make_float2(c4.x - c6.x, c4.y - c6.y);
    float2 d5 = make_float2(c5.x + t7.x, c5.y + t7.y);
    float2 d7 = make_float2(c5.x - t7.x, c5.y - t7.y);
    float2 w1 = make_float2(r, sgn * r), w3 = make_float2(-r, sgn * r);
    float2 t5 = make_float2(d5.x * w1.x - d5.y * w1.y, d5.x * w1.y + d5.y * w1.x);
    float2 t6 = make_float2(-sgn * d6.y, sgn * d6.x);
    float2 t7b = make_float2(d7.x * w3.x - d7.y * w3.y, d7.x * w3.y + d7.y * w3.x);
    a[0] = make_float2(d0.x + d4.x, d0.y + d4.y);
    a[4] = make_float2(d0.x - d4.x, d0.y - d4.y);
    a[1] = make_float2(d1.x + t5.x, d1.y + t5.y);
    a[5] = make_float2(d1.x - t5.x, d1.y - t5.y);
    a[2] = make_float2(d2.x + t6.x, d2.y + t6.y);
    a[6] = make_float2(d2.x - t6.x, d2.y - t6.y);
    a[3] = make_float2(d3.x + t7b.x, d3.y + t7b.y);
    a[7] = make_float2(d3.x - t7b.x, d3.y - t7b.y);
}

// ---------- register twiddle cache ----------
// tw1[k1] = exp(-2*pi*i*u*k1/128); tw2[b] = exp(-2*pi*i*b/16).
// Forward: tsgn=+1. Inverse: conjugate -> tsgn=-1.
__device__ __forceinline__ void make_twiddles(int u, float2* tw1, float2* tw2) {
#pragma unroll
    for (int k = 0; k < 8; ++k) {
        float sn, cs;
        __sincosf(-0.049087385212340517f * (float)(u * k), &sn, &cs);
        tw1[k] = make_float2(cs, sn);
    }
#pragma unroll
    for (int b = 0; b < 8; ++b) {
        float sn, cs;
        __sincosf(-0.39269908169872414f * (float)b, &sn, &cs);
        tw2[b] = make_float2(cs, sn);
    }
}

// ---------- TWO interleaved 128-pt FFTs on LDS plane lines (in-place) -----
// Each 16-lane group owns two disjoint lines (lb0, lb1). Interleaving them
// doubles LDS MLP and VALU work per round-trip: the serial chain
// read->dft->write->read->dft->write is traversed ONCE for both lines
// instead of twice (the asm clobbers previously serialized the two calls).
// Rotated slot mapping slot(k1,j)=k1*16+((j+2*k1)&15) as before.
__device__ __forceinline__ void fft128_plane2(float2* pl, int lb0, int lb1,
                                              int stride, int u, float sgn,
                                              float tsgn, const float2* tw1,
                                              const float2* tw2) {
    float2 v0[8], v1[8];
#pragma unroll
    for (int n1 = 0; n1 < 8; ++n1) {
        int o = (16 * n1 + u) * stride;
        v0[n1] = pl[lb0 + o];
        v1[n1] = pl[lb1 + o];
    }
    dft8(v0, sgn); dft8(v1, sgn);
#pragma unroll
    for (int k1 = 0; k1 < 8; ++k1) {
        float cs = tw1[k1].x, sn = tw1[k1].y * tsgn;
        int slot = (k1 * 16 + ((u + 2 * k1) & 15)) * stride;
        float2 y0 = v0[k1], y1 = v1[k1];
        pl[lb0 + slot] = make_float2(y0.x * cs - y0.y * sn, y0.x * sn + y0.y * cs);
        pl[lb1 + slot] = make_float2(y1.x * cs - y1.y * sn, y1.x * sn + y1.y * cs);
    }
    asm volatile("" ::: "memory");   // write->read order at compile level
    int k1 = u & 7, c = u >> 3;
    float2 w0[8], w1[8];
#pragma unroll
    for (int b = 0; b < 8; ++b) {
        int sa = (k1 * 16 + ((b + 2 * k1) & 15)) * stride;
        int sb = (k1 * 16 + ((8 + b + 2 * k1) & 15)) * stride;
        float2 za0 = pl[lb0 + sa], zb0 = pl[lb0 + sb];
        float2 za1 = pl[lb1 + sa], zb1 = pl[lb1 + sb];
        float2 s0 = c ? make_float2(za0.x - zb0.x, za0.y - zb0.y)
                      : make_float2(za0.x + zb0.x, za0.y + zb0.y);
        float2 s1 = c ? make_float2(za1.x - zb1.x, za1.y - zb1.y)
                      : make_float2(za1.x + zb1.x, za1.y + zb1.y);
        if (c && b) {
            float cs = tw2[b].x, sn = tw2[b].y * tsgn;
            s0 = make_float2(s0.x * cs - s0.y * sn, s0.x * sn + s0.y * cs);
            s1 = make_float2(s1.x * cs - s1.y * sn, s1.x * sn + s1.y * cs);
        }
        w0[b] = s0; w1[b] = s1;
    }
    dft8(w0, sgn); dft8(w1, sgn);
    asm volatile("" ::: "memory");
#pragma unroll
    for (int k3 = 0; k3 < 8; ++k3) {
        int o = (u + 16 * k3) * stride;
        pl[lb0 + o] = w0[k3];
        pl[lb1 + o] = w1[k3];
    }
}

// ---------- 128-pt FFT through a block-shared Z buffer (single payload) ----
__device__ __forceinline__ void fft128_Z(float2* Z, int l, int u, float sgn,
                                         float tsgn, const float2* tw1,
                                         const float2* tw2, float2* v) {
    __syncthreads();
    dft8(v, sgn);
#pragma unroll
    for (int k1 = 0; k1 < 8; ++k1) {
        float cs = tw1[k1].x, sn = tw1[k1].y * tsgn;
        float2 y = v[k1];
        Z[l * 137 + k1 * 17 + u] = make_float2(y.x * cs - y.y * sn, y.x * sn + y.y * cs);
    }
    __syncthreads();
    int k1 = u & 7, c = u >> 3;
    float2 w[8];
#pragma unroll
    for (int b = 0; b < 8; ++b) {
        float2 za = Z[l * 137 + k1 * 17 + b];
        float2 zb = Z[l * 137 + k1 * 17 + 8 + b];
        float2 s = c ? make_float2(za.x - zb.x, za.y - zb.y)
                     : make_float2(za.x + zb.x, za.y + zb.y);
        if (c && b) {
            float cs = tw2[b].x, sn = tw2[b].y * tsgn;
            s = make_float2(s.x * cs - s.y * sn, s.x * sn + s.y * cs);
        }
        w[b] = s;
    }
    dft8(w, sgn);
#pragma unroll
    for (int k3 = 0; k3 < 8; ++k3) v[k3] = w[k3];
}

// ---------- TWO interleaved 128-pt FFTs through two Z buffers ----------
// For the g1/g2 inverse pair in fft_x_fused: halves the barrier count
// (2 instead of 4) and doubles ILP between barriers.
__device__ __forceinline__ void fft128_Z2(float2* Z1, float2* Z2, int l, int u,
                                          float sgn, float tsgn,
                                          const float2* tw1, const float2* tw2,
                                          float2* va, float2* vb) {
    __syncthreads();
    dft8(va, sgn); dft8(vb, sgn);
#pragma unroll
    for (int k1 = 0; k1 < 8; ++k1) {
        float cs = tw1[k1].x, sn = tw1[k1].y * tsgn;
        float2 ya = va[k1], yb = vb[k1];
        Z1[l * 137 + k1 * 17 + u] = make_float2(ya.x * cs - ya.y * sn, ya.x * sn + ya.y * cs);
        Z2[l * 137 + k1 * 17 + u] = make_float2(yb.x * cs - yb.y * sn, yb.x * sn + yb.y * cs);
    }
    __syncthreads();
    int k1 = u & 7, c = u >> 3;
    float2 wa[8], wb[8];
#pragma unroll
    for (int b = 0; b < 8; ++b) {
        float2 za1 = Z1[l * 137 + k1 * 17 + b];
        float2 zb1 = Z1[l * 137 + k1 * 17 + 8 + b];
        float2 za2 = Z2[l * 137 + k1 * 17 + b];
        float2 zb2 = Z2[l * 137 + k1 * 17 + 8 + b];
        float2 s1 = c ? make_float2(za1.x - zb1.x, za1.y - zb1.y)
                      : make_float2(za1.x + zb1.x, za1.y + zb1.y);
        float2 s2 = c ? make_float2(za2.x - zb2.x, za2.y - zb2.y)
                      : make_float2(za2.x + zb2.x, za2.y + zb2.y);
        if (c && b) {
            float cs = tw2[b].x, sn = tw2[b].y * tsgn;
            s1 = make_float2(s1.x * cs - s1.y * sn, s1.x * sn + s1.y * cs);
            s2 = make_float2(s2.x * cs - s2.y * sn, s2.x * sn + s2.y * cs);
        }
        wa[b] = s1; wb[b] = s2;
    }
    dft8(wa, sgn); dft8(wb, sgn);
#pragma unroll
    for (int k3 = 0; k3 < 8; ++k3) { va[k3] = wa[k3]; vb[k3] = wb[k3]; }
}

// ---------- input dtype detection ----------
__global__ void detect_kernel(const unsigned int* __restrict__ words,
                              int* __restrict__ flag) {
    int t = threadIdx.x;
    unsigned long long m = __ballot((words[t] >> 15) & 1u);
    if (t == 0) *flag = (__popcll(m) > 16) ? 0 : 1;  // 0 = f32 input, 1 = bf16
}

// ---------- CIC paint: 16^3 core + halo2 (512 blocks x 1024 threads) ----------
// R4 version. LDS-atomic floor ~98us (invariant across R0-R12 configs).
__global__ __launch_bounds__(1024, 4)
void paint_lds(const void* __restrict__ pos, float* __restrict__ grid,
               const int* __restrict__ flag) {
    __shared__ float tile[CELLS];
    int t = threadIdx.x;
    int bi = blockIdx.x;
    int tz = bi & 7, ty = (bi >> 3) & 7, tx = bi >> 6;
    int x0 = tx * 16, y0 = ty * 16, z0 = tz * 16;
    for (int i = t; i < CELLS; i += 1024) tile[i] = 0.f;
    int isbf16 = *flag;
    __syncthreads();

    int zg = t & 3, dy = (t >> 2) & 15, dx = t >> 6;
    int p0 = (((x0 + dx) << 7) + (y0 + dy)) * 128 + z0 + 4 * zg;

    float P[4][3];
    if (isbf16) {
        const uint2* q = (const uint2*)((const char*)pos + 6ll * p0);  // 24B, 8B-aligned
        uint2 a = q[0], b = q[1], c = q[2];
        unsigned int w[6] = {a.x, a.y, b.x, b.y, c.x, c.y};
#pragma unroll
        for (int e = 0; e < 12; ++e) {
            unsigned short h = (e & 1) ? (unsigned short)(w[e >> 1] >> 16)
                                       : (unsigned short)(w[e >> 1] & 0xffffu);
            P[e / 3][e % 3] = bf2f(h);
        }
    } else {
        const float4* q = (const float4*)((const float*)pos + 3ll * p0);  // 48B, 16B-aligned
        float4 a = q[0], b = q[1], c = q[2];
        P[0][0] = a.x; P[0][1] = a.y; P[0][2] = a.z;
        P[1][0] = a.w; P[1][1] = b.x; P[1][2] = b.y;
        P[2][0] = b.z; P[2][1] = b.w; P[2][2] = c.x;
        P[3][0] = c.y; P[3][1] = c.z; P[3][2] = c.w;
    }

#pragma unroll
    for (int it = 0; it < 4; ++it) {
        float P0 = P[it][0], P1 = P[it][1], P2 = P[it][2];
        float f0 = floorf(P0), f1 = floorf(P1), f2 = floorf(P2);
        int ix = (int)f0, iy = (int)f1, iz = (int)f2;
        float wx1 = P0 - f0, wy1 = P1 - f1, wz1 = P2 - f2;
        float wx0 = 1.f - wx1, wy0 = 1.f - wy1, wz0 = 1.f - wz1;
        int lx = (ix - x0 + 2) & 127, ly = (iy - y0 + 2) & 127;
        int lz = (iz - z0 + 2) & 127;
        if (lx <= 19 && ly <= 19 && lz <= 19) {
            int b00 = (lx * SP + ly) * SP + lz;
            int b01 = b00 + SP;
            int b10 = b00 + SP * SP;
            int b11 = b10 + SP;
            ldsAddF(&tile[b00],     wx0 * wy0 * wz0);
            ldsAddF(&tile[b00 + 1], wx0 * wy0 * wz1);
            ldsAddF(&tile[b01],     wx0 * wy1 * wz0);
            ldsAddF(&tile[b01 + 1], wx0 * wy1 * wz1);
            ldsAddF(&tile[b10],     wx1 * wy0 * wz0);
            ldsAddF(&tile[b10 + 1], wx1 * wy0 * wz1);
            ldsAddF(&tile[b11],     wx1 * wy1 * wz0);
            ldsAddF(&tile[b11 + 1], wx1 * wy1 * wz1);
        } else {  // rare outlier: global fallback
            int gx = ix & 127, gy = iy & 127, gz = iz & 127;
            int hx = (gx + 1) & 127, hy = (gy + 1) & 127, hz = (gz + 1) & 127;
            glbAddF(&grid[((gx << 7) + gy) * 128 + gz], wx0 * wy0 * wz0);
            glbAddF(&grid[((gx << 7) + gy) * 128 + hz], wx0 * wy0 * wz1);
            glbAddF(&grid[((gx << 7) + hy) * 128 + gz], wx0 * wy1 * wz0);
            glbAddF(&grid[((gx << 7) + hy) * 128 + hz], wx0 * wy1 * wz1);
            glbAddF(&grid[((hx << 7) + gy) * 128 + gz], wx1 * wy0 * wz0);
            glbAddF(&grid[((hx << 7) + gy) * 128 + hz], wx1 * wy0 * wz1);
            glbAddF(&grid[((hx << 7) + hy) * 128 + gz], wx1 * wy1 * wz0);
            glbAddF(&grid[((hx << 7) + hy) * 128 + hz], wx1 * wy1 * wz1);
        }
    }
    __syncthreads();
    for (int i = t; i < CELLS; i += 1024) {
        float v = tile[i];
        if (v != 0.f) {
            int lx = i / (SP * SP);
            int r  = i - lx * (SP * SP);
            int ly = r / SP, lz = r - ly * SP;
            int gx = (x0 - 2 + lx) & 127, gy = (y0 - 2 + ly) & 127;
            int gz = (z0 - 2 + lz) & 127;
            glbAddF(&grid[((gx << 7) + gy) * 128 + gz], v);
        }
    }
}

// ---------- fused forward z+y FFT: one x-plane per block, in LDS ----------
__global__ __launch_bounds__(1024)
void fft_zy_fwd(const float* __restrict__ delta, float2* __restrict__ A) {
    __shared__ float2 pl[128 * PSTR];   // 132 KB (gfx950 LDS = 160 KB/CU)
    int t = threadIdx.x, x = blockIdx.x;
    const float4* src = (const float4*)(delta + (long)x * MESH2);
    for (int i = t; i < MESH2 / 4; i += 1024) {
        float4 d = src[i];
        int y = i >> 5, z0 = (i & 31) * 4;
        float2* row = &pl[y * PSTR + z0];
        row[0] = make_float2(d.x, 0.f); row[1] = make_float2(d.y, 0.f);
        row[2] = make_float2(d.z, 0.f); row[3] = make_float2(d.w, 0.f);
    }
    int u = t & 15, ln = t >> 4;            // 64 intra-wave line groups
    float2 tw1[8], tw2[8];
    make_twiddles(u, tw1, tw2);
    __syncthreads();
    fft128_plane2(pl, ln * PSTR, (ln + 64) * PSTR, 1, u, -1.f, 1.f, tw1, tw2); // z
    __syncthreads();
    fft128_plane2(pl, ln, ln + 64, PSTR, u, -1.f, 1.f, tw1, tw2);              // y
    __syncthreads();
    float4* dst = (float4*)(A + (long)x * MESH2);
    for (int i = t; i < MESH2 / 2; i += 1024) {
        int y = i >> 6, z0 = (i & 63) * 2;
        float2 e0 = pl[y * PSTR + z0], e1 = pl[y * PSTR + z0 + 1];
        dst[i] = make_float4(e0.x, e0.y, e1.x, e1.y);
    }
}

// ---------- fused x fwd-FFT + k-space kernel + x inv-FFT (both volumes) ----
__global__ __launch_bounds__(256)
void fft_x_fused(float2* __restrict__ A, float2* __restrict__ G2) {
    __shared__ float2 Z1[16 * 137];
    __shared__ float2 Z2[16 * 137];
    int t = threadIdx.x;
    int l = t & 15, u = t >> 4;
    int L = blockIdx.x * 16 + l;
    const float invN3 = 1.0f / 2097152.0f;
    float2 tw1[8], tw2[8];
    make_twiddles(u, tw1, tw2);
    float2 X[8];
#pragma unroll
    for (int n1 = 0; n1 < 8; ++n1) X[n1] = A[(long)(16 * n1 + u) * MESH2 + L];
    fft128_Z(Z1, l, u, -1.f, 1.f, tw1, tw2, X);  // X[k3] = delta_k at kx=u+16*k3
    float ky = kfreq(L >> 7), kz = kfreq(L & 127);
    float2 g1[8], g2[8];
#pragma unroll
    for (int k3 = 0; k3 < 8; ++k3) {
        int k = u + 16 * k3;
        float kx = kfreq(k);
        float kk = kx * kx + ky * ky + kz * kz;
        float f = 0.f;
        if (kk > 0.f) f = -__expf(-0.09f / kk - kk * kk) / kk * invN3;
        float a = X[k3].x * f, b = X[k3].y * f;           // Pv
        g1[k3] = make_float2(-kx * b - ky * a, kx * a - ky * b);  // (ikx+i*iky)Pv
        g2[k3] = make_float2(-kz * b, kz * a);                    // ikz*Pv
    }
    // two inverse transforms interleaved through two Z buffers (conj twiddles)
    fft128_Z2(Z1, Z2, l, u, 1.f, -1.f, tw1, tw2, g1, g2);
#pragma unroll
    for (int k3 = 0; k3 < 8; ++k3) {
        long idx = (long)(u + 16 * k3) * MESH2 + L;
        A[idx]  = g1[k3];
        G2[idx] = g2[k3];
    }
}

// ---------- fused inverse y+z FFT + real extraction (grid 128 x 2 vols) ----
__global__ __launch_bounds__(1024)
void fft_yz_inv(const float2* __restrict__ G1, const float2* __restrict__ G2,
                float* __restrict__ F0, float* __restrict__ F1,
                float* __restrict__ F2) {
    __shared__ float2 pl[128 * PSTR];
    int t = threadIdx.x, x = blockIdx.x, vol = blockIdx.y;
    const float4* src = (const float4*)((vol ? G2 : G1) + (long)x * MESH2);
    for (int i = t; i < MESH2 / 2; i += 1024) {
        float4 d = src[i];
        int y = i >> 6, z0 = (i & 63) * 2;
        pl[y * PSTR + z0]     = make_float2(d.x, d.y);
        pl[y * PSTR + z0 + 1] = make_float2(d.z, d.w);
    }
    int u = t & 15, ln = t >> 4;
    float2 tw1[8], tw2[8];
    make_twiddles(u, tw1, tw2);
    __syncthreads();
    fft128_plane2(pl, ln * PSTR, (ln + 64) * PSTR, 1, u, 1.f, -1.f, tw1, tw2); // z
    __syncthreads();
    fft128_plane2(pl, ln, ln + 64, PSTR, u, 1.f, -1.f, tw1, tw2);              // y
    __syncthreads();
    long b = (long)x * MESH2;
    if (vol == 0) {
        for (int i = t; i < MESH2; i += 1024) {
            float2 v = pl[(i >> 7) * PSTR + (i & 127)];
            F0[b + i] = v.x;   // Fx
            F1[b + i] = v.y;   // Fy
        }
    } else {
        for (int i = t; i < MESH2; i += 1024)
            F2[b + i] = pl[(i >> 7) * PSTR + (i & 127)].x;   // Fz
    }
}

// ---------- CIC read + position update (writes pos half [0,24Mi) ONLY) ----------
__global__ __launch_bounds__(256)
void update_pos(const void* __restrict__ pos,
                const float* __restrict__ Fx, const float* __restrict__ Fy,
                const float* __restrict__ Fz, float* __restrict__ out,
                const int* __restrict__ flag, int n) {
    int p = blockIdx.x * blockDim.x + threadIdx.x;
    if (p >= n) return;
    int isbf16 = *flag;
    float P0 = load_elem(pos, 3 * p + 0, isbf16);
    float P1 = load_elem(pos, 3 * p + 1, isbf16);
    float P2 = load_elem(pos, 3 * p + 2, isbf16);
    float f0 = floorf(P0), f1 = floorf(P1), f2 = floorf(P2);
    int ix = ((int)f0) & 127, iy = ((int)f1) & 127, iz = ((int)f2) & 127;
    float wx1 = P0 - f0, wy1 = P1 - f1, wz1 = P2 - f2;
    float wx0 = 1.f - wx1, wy0 = 1.f - wy1, wz0 = 1.f - wz1;
    int jx = (ix + 1) & 127, jy = (iy + 1) & 127, jz = (iz + 1) & 127;
    int b00 = (ix * MESH + iy) * MESH;
    int b01 = (ix * MESH + jy) * MESH;
    int b10 = (jx * MESH + iy) * MESH;
    int b11 = (jx * MESH + jy) * MESH;
    float fx = 0.f, fy = 0.f, fz = 0.f;
    int f; float w;
    f = b00 + iz; w = wx0 * wy0 * wz0; fx += w * Fx[f]; fy += w * Fy[f]; fz += w * Fz[f];
    f = b00 + jz; w = wx0 * wy0 * wz1; fx += w * Fx[f]; fy += w * Fy[f]; fz += w * Fz[f];
    f = b01 + iz; w = wx0 * wy1 * wz0; fx += w * Fx[f]; fy += w * Fy[f]; fz += w * Fz[f];
    f = b01 + jz; w = wx0 * wy1 * wz1; fx += w * Fx[f]; fy += w * Fy[f]; fz += w * Fz[f];
    f = b10 + iz; w = wx1 * wy0 * wz0; fx += w * Fx[f]; fy += w * Fy[f]; fz += w * Fz[f];
    f = b10 + jz; w = wx1 * wy0 * wz1; fx += w * Fx[f]; fy += w * Fy[f]; fz += w * Fz[f];
    f = b11 + iz; w = wx1 * wy1 * wz0; fx += w * Fx[f]; fy += w * Fy[f]; fz += w * Fz[f];
    f = b11 + jz; w = wx1 * wy1 * wz1; fx += w * Fx[f]; fy += w * Fy[f]; fz += w * Fz[f];
    out[3 * p + 0] = P0 + 0.2f * fx;
    out[3 * p + 1] = P1 + 0.2f * fy;
    out[3 * p + 2] = P2 + 0.2f * fz;
}

// ---------- vel passthrough (second half of out; runs AFTER update_pos) ----------
// Vectorized: one float4 store (and one float4/uint2 load) per thread.
__global__ __launch_bounds__(256)
void copy_vel(const void* __restrict__ vel, float* __restrict__ dst,
              const int* __restrict__ flag, int m) {   // m = 3n floats
    int i0 = (blockIdx.x * blockDim.x + threadIdx.x) * 4;
    if (i0 >= m) return;
    if (*flag) {  // bf16: 4 elems = 8 B
        uint2 w = *(const uint2*)((const char*)vel + (size_t)i0 * 2);
        *(float4*)(dst + i0) = make_float4(
            bf2f((unsigned short)(w.x & 0xffffu)), bf2f((unsigned short)(w.x >> 16)),
            bf2f((unsigned short)(w.y & 0xffffu)), bf2f((unsigned short)(w.y >> 16)));
    } else {      // f32: 16 B
        *(float4*)(dst + i0) = *(const float4*)((const float*)vel + i0);
    }
}

// ---------- launch ----------
// ws (32Mi+4K): [0,4K) flag | A @ [4K,16Mi+4K) | F0 @ +16Mi | F1 @ +24Mi.
// d_out (48Mi): delta @ [0,8Mi) | G2 @ [24Mi,40Mi) | F2 @ [40Mi,48Mi).
extern "C" void kernel_launch(void* const* d_in, const int* in_sizes, int n_in,
                              void* d_out, int out_size, void* d_ws, size_t ws_size,
                              hipStream_t stream) {
    int n = in_sizes[0] / 3;
    const void* pos = d_in[0];
    const void* vel = d_in[1];
    float* out = (float*)d_out;

    char* ws = (char*)d_ws;
    int*    flag = (int*)ws;
    float2* A  = (float2*)(ws + 4096);
    float*  F0 = (float*)(ws + 4096 + (16u << 20));
    float*  F1 = (float*)(ws + 4096 + (24u << 20));
    float*  delta = (float*)d_out;                           // [0, 8Mi)
    float2* G2 = (float2*)((char*)d_out + (24u << 20));      // [24Mi, 40Mi)
    float*  F2 = (float*)((char*)d_out + (40u << 20));       // [40Mi, 48Mi)

    detect_kernel<<<1, 64, 0, stream>>>((const unsigned int*)pos, flag);
    hipMemsetAsync(delta, 0, MESH3 * sizeof(float), stream);
    paint_lds<<<512, 1024, 0, stream>>>(pos, delta, flag);

    fft_zy_fwd<<<128, 1024, 0, stream>>>(delta, A);
    fft_x_fused<<<1024, 256, 0, stream>>>(A, G2);
    fft_yz_inv<<<dim3(128, 2), 1024, 0, stream>>>(A, G2, F0, F1, F2);

    update_pos<<<(n + 255) / 256, 256, 0, stream>>>(pos, F0, F1, F2, out, flag, n);
    int m = 3 * n;
    copy_vel<<<(m / 4 + 255) / 256, 256, 0, stream>>>(vel, out + m, flag, m);
}